// Round 15
// baseline (24.176 us; speedup 1.0000x reference)
//
#include <hip/hip_runtime.h>
#include <math.h>

#define MAGIC 0x5F3759DFu
typedef unsigned int u32;

__device__ __forceinline__ void bar_lds(){
  asm volatile("s_waitcnt lgkmcnt(0)\n\ts_barrier" ::: "memory");
}
__device__ __forceinline__ void bar_vm0(){
  asm volatile("s_waitcnt vmcnt(0) lgkmcnt(0)\n\ts_barrier" ::: "memory");
}
__device__ __forceinline__ void bar_vm8(){
  asm volatile("s_waitcnt vmcnt(8) lgkmcnt(0)\n\ts_barrier" ::: "memory");
}

__device__ inline float wsum(float v){
  #pragma unroll
  for (int o=32;o;o>>=1) v += __shfl_xor(v,o,64);
  return v;
}
__device__ inline float wmax(float v){
  #pragma unroll
  for (int o=32;o;o>>=1) v = fmaxf(v,__shfl_xor(v,o,64));
  return v;
}
__device__ inline float hsum32(float v){
  #pragma unroll
  for (int o=16;o;o>>=1) v += __shfl_xor(v,o,64);
  return v;
}
__device__ __forceinline__ void stageW(const float* g, float* l, int nfloats,
                                       int wid, int lane){
  const int nch = nfloats>>8;
  for (int c=wid; c<nch; c+=8)
    __builtin_amdgcn_global_load_lds(
      (__attribute__((address_space(1))) u32*)(void*)(g+(c<<8)+(lane<<2)),
      (__attribute__((address_space(3))) u32*)(void*)(l+(c<<8)), 16, 0, 0);
}
__device__ __forceinline__ void pf(const float* p, int nfloats, int tid){
  float4 acc={0.f,0.f,0.f,0.f};
  const int nq=nfloats>>2;
  for (int i=tid;i<nq;i+=512){
    const float4 v=((const float4*)p)[i];
    acc.x+=v.x; acc.y+=v.y; acc.z+=v.z; acc.w+=v.w;
  }
  asm volatile("" :: "v"(acc.x),"v"(acc.y),"v"(acc.z),"v"(acc.w));
}
__device__ __forceinline__ void poll1(const u32* f, int lane){
  u32 v=0;
  do {
    if (lane==0) v=__hip_atomic_load(f,__ATOMIC_ACQUIRE,__HIP_MEMORY_SCOPE_AGENT);
    v=(u32)__shfl((int)v,0,64);
    if (v!=MAGIC) __builtin_amdgcn_s_sleep(1);
  } while (v!=MAGIC);
}
__device__ __forceinline__ float aload(const float* p){
  return __hip_atomic_load(p,__ATOMIC_RELAXED,__HIP_MEMORY_SCOPE_AGENT);
}
__device__ __forceinline__ void astore(float* p, float v){
  __hip_atomic_store(p,v,__ATOMIC_RELAXED,__HIP_MEMORY_SCOPE_AGENT);
}

// amp-reduced C-main (proven R14)
template<int F,int VH,int N>
__device__ __forceinline__ void cmain2(int lt, const float* slot,
                                       const float* ZBp, float* PBp){
  constexpr int CH = 128/F;
  const int c4 = lt&31, r = lt>>5;
  const int fh = r & (F-1), vh = r / F;
  const int f0 = fh*CH;
  const float4* slot4 = (const float4*)slot;
  float4 acc[VH];
  #pragma unroll
  for (int i=0;i<VH;++i) acc[i]=make_float4(0.f,0.f,0.f,0.f);
  #pragma unroll
  for (int f=0; f<CH; ++f){
    const float4 w4 = slot4[(f0+f)*32 + c4];
    #pragma unroll
    for (int i=0;i<VH;++i){
      const float zv = ZBp[((vh*VH+i)<<7) + f0 + f];
      acc[i].x+=zv*w4.x; acc[i].y+=zv*w4.y; acc[i].z+=zv*w4.z; acc[i].w+=zv*w4.w;
    }
  }
  #pragma unroll
  for (int i=0;i<VH;++i){
    acc[i].x+=__shfl_xor(acc[i].x,32,64);
    acc[i].y+=__shfl_xor(acc[i].y,32,64);
    acc[i].z+=__shfl_xor(acc[i].z,32,64);
    acc[i].w+=__shfl_xor(acc[i].w,32,64);
  }
  if (!(r&1)){
    const int fp = fh>>1;
    float4* P4=(float4*)PBp;
    #pragma unroll
    for (int i=0;i<VH;++i)
      P4[(fp*N + vh*VH + i)*32 + c4] = acc[i];
  }
}

// ws float layout: pg[0..255] flagG@256 | ps[320..575] flagS@576
//                  h1[640..895] flag@896 | h2[960..1215] flag@1216
__global__ __launch_bounds__(512,1) void net_kernel(
    const float* __restrict__ gp_x, const float* __restrict__ sp_x,
    const int* __restrict__ gp_src, const int* __restrict__ gp_dst,
    const int* __restrict__ sp_src, const int* __restrict__ sp_dst,
    const float* __restrict__ g_W0, const float* __restrict__ g_W,
    const float* __restrict__ g_b,  const float* __restrict__ g_pWrel,
    const float* __restrict__ g_pbrel, const float* __restrict__ g_pWroot,
    const float* __restrict__ g_linW, const float* __restrict__ g_linb,
    const float* __restrict__ s_W0, const float* __restrict__ s_W,
    const float* __restrict__ s_b,  const float* __restrict__ s_pWrel,
    const float* __restrict__ s_pbrel, const float* __restrict__ s_pWroot,
    const float* __restrict__ s_linW, const float* __restrict__ s_linb,
    const float* __restrict__ fcW, const float* __restrict__ fcb,
    const float* __restrict__ lnw, const float* __restrict__ lnb,
    float* __restrict__ wsbuf, float* __restrict__ out)
{
  __shared__ __align__(16) float slotA[16384];   // W1 -> W3 (DMA)
  __shared__ __align__(16) float slotB[16384];   // W2 -> linW (DMA)
  __shared__ __align__(16) float XBx[16][128];
  __shared__ __align__(16) float ZBraw[1024];
  __shared__ __align__(16) float PBf[2048];      // C-phase partials (8KB)
  __shared__ __align__(16) float wrelL[512], wrootL[512];
  __shared__ __align__(16) float Adn[256], Mdn[256];
  __shared__ float d1P[64], d2P[64];
  __shared__ float yA[128];
  __shared__ float tsA[8]; __shared__ int permA[8];
  __shared__ float fcin[256]; __shared__ float wpart[16];

  const int lt  = threadIdx.x;
  const int bid = blockIdx.x;
  const int wid = lt>>6, lane = lt&63;
  const int qfc = (wid<<3)+(lane&7);             // output quad 0..63

  // ============ prefetch army (bids 5..18): fine slices ============
  if (bid >= 5){
    if (bid==5){ pf(g_W0,5760,lt); pf(g_pWrel,512,lt); pf(g_pWroot,512,lt);
                 pf(g_b,512,lt);   pf(g_linb,128,lt); }
    else if (bid==6){ pf(s_W0,5760,lt); pf(s_pWrel,512,lt); pf(s_pWroot,512,lt);
                 pf(s_b,512,lt);   pf(s_linb,128,lt); }
    else if (bid<=10) pf(g_W + (bid-7)*12288, 12288, lt);
    else if (bid<=14) pf(s_W + (bid-11)*12288, 12288, lt);
    else if (bid<=16) pf(g_linW + (bid-15)*8192, 8192, lt);
    else              pf(s_linW + (bid-17)*8192, 8192, lt);
    return;
  }

  // ============ FC pipeline blocks (bids 2,3,4 -> layers 1,2,3) ============
  if (bid >= 2){
    const int L = bid-1;                         // 1,2,3
    const int f0fc=(lane>>3)<<5;                 // 32-input chunk
    float4 wr[32];
    #pragma unroll
    for (int t=0;t<32;++t) wr[t]=*(const float4*)(fcW+(L<<16)+(f0fc+t)*256+(qfc<<2));
    const float4 bb=*(const float4*)(fcb+(L<<8)+(qfc<<2));
    float4 lw={0,0,0,0}, lb2={0,0,0,0};
    if (L<3){ lw=*(const float4*)(lnw+(L<<8)+(qfc<<2)); lb2=*(const float4*)(lnb+(L<<8)+(qfc<<2)); }

    float zr[32];
    if (bid==2){
      // FC1: sum worker FC0-partials + fcb0, LN0, relu -> fcin
      float b0=0.f,w0=0.f,l0=0.f;
      if (lt<256){ b0=fcb[lt]; w0=lnw[lt]; l0=lnb[lt]; }
      poll1((const u32*)(wsbuf+256), lane);
      poll1((const u32*)(wsbuf+576), lane);
      float h=0.f;
      if (lt<256){
        h = aload(wsbuf+lt) + aload(wsbuf+320+lt) + b0;
        float s=wsum(h), s2=wsum(h*h);
        if (lane==0){ wpart[wid]=s; wpart[8+wid]=s2; }
      }
      bar_lds();
      if (lt<256){
        const float S =wpart[0]+wpart[1]+wpart[2]+wpart[3];
        const float S2=wpart[8]+wpart[9]+wpart[10]+wpart[11];
        const float mu=S*(1.f/256.f);
        const float ri=rsqrtf(S2*(1.f/256.f)-mu*mu+1e-5f);
        fcin[lt]=fmaxf((h-mu)*ri*w0+l0,0.f);
      }
      bar_lds();
      #pragma unroll
      for (int t=0;t<32;++t) zr[t]=fcin[f0fc+t];
    } else {
      const int floff = (bid==3)?896:1216;
      const int srcoff= (bid==3)?640:960;
      poll1((const u32*)(wsbuf+floff), lane);
      #pragma unroll
      for (int t=0;t<32;++t) zr[t]=aload(wsbuf+srcoff+f0fc+t);
    }
    float4 a={0.f,0.f,0.f,0.f};
    #pragma unroll
    for (int t=0;t<32;++t){
      a.x+=zr[t]*wr[t].x; a.y+=zr[t]*wr[t].y; a.z+=zr[t]*wr[t].z; a.w+=zr[t]*wr[t].w;
    }
    #pragma unroll
    for (int m=8;m<64;m<<=1){
      a.x+=__shfl_xor(a.x,m,64); a.y+=__shfl_xor(a.y,m,64);
      a.z+=__shfl_xor(a.z,m,64); a.w+=__shfl_xor(a.w,m,64);
    }
    if (bid==4){
      if (lane<8){
        float4 r; r.x=a.x+bb.x; r.y=a.y+bb.y; r.z=a.z+bb.z; r.w=a.w+bb.w;
        *(float4*)(out+(qfc<<2))=r;
      }
      return;
    }
    const bool act=(lane<8);
    float4 hv={0.f,0.f,0.f,0.f};
    if (act){
      hv.x=a.x+bb.x; hv.y=a.y+bb.y; hv.z=a.z+bb.z; hv.w=a.w+bb.w;
      float s=hv.x+hv.y+hv.z+hv.w;
      float s2=hv.x*hv.x+hv.y*hv.y+hv.z*hv.z+hv.w*hv.w;
      #pragma unroll
      for (int m=1;m<8;m<<=1){ s+=__shfl_xor(s,m,64); s2+=__shfl_xor(s2,m,64); }
      if (lane==0){ wpart[wid]=s; wpart[8+wid]=s2; }
    }
    bar_lds();
    if (act){
      float S=0.f,S2=0.f;
      #pragma unroll
      for (int w2=0;w2<8;++w2){ S+=wpart[w2]; S2+=wpart[8+w2]; }
      const float mu=S*(1.f/256.f);
      const float ri=rsqrtf(S2*(1.f/256.f)-mu*mu+1e-5f);
      float* dst=wsbuf + ((bid==2)?640:960) + (qfc<<2);
      astore(dst+0,fmaxf((hv.x-mu)*ri*lw.x+lb2.x,0.f));
      astore(dst+1,fmaxf((hv.y-mu)*ri*lw.y+lb2.y,0.f));
      astore(dst+2,fmaxf((hv.z-mu)*ri*lw.z+lb2.z,0.f));
      astore(dst+3,fmaxf((hv.w-mu)*ri*lw.w+lb2.w,0.f));
    }
    bar_vm0();
    if (lt==0) __hip_atomic_store((u32*)(wsbuf+((bid==2)?896:1216)),MAGIC,__ATOMIC_RELEASE,__HIP_MEMORY_SCOPE_AGENT);
    return;
  }

  // ============ GNN worker blocks (bids 0,1) — R14 core + FC0 fold ============
  const int br = bid;
  const float* x0    = br ? sp_x    : gp_x;
  const int*   srcg  = br ? sp_src  : gp_src;
  const int*   dstg  = br ? sp_dst  : gp_dst;
  const float* W0    = br ? s_W0    : g_W0;
  const float* Wl    = br ? s_W     : g_W;
  const float* bl    = br ? s_b     : g_b;
  const float* wrel  = br ? s_pWrel : g_pWrel;
  const float* brel  = br ? s_pbrel : g_pbrel;
  const float* wroot = br ? s_pWroot: g_pWroot;
  const float* linWg = br ? s_linW  : g_linW;
  const float* linb  = br ? s_linb  : g_linb;
  float* wsOut = wsbuf + br*320;
  u32*   wsFlag = (u32*)(wsbuf + 256 + br*320);
  const int f0fc=(lane>>3)<<4;                   // 16-input chunk (FC0 half)

  float xv[4];
  #pragma unroll
  for (int r=0;r<4;++r){
    const int i=lt+(r<<9), v=i>>7, f=i&127;
    xv[r] = (f<45)? x0[v*45+f] : 0.f;
  }
  int es=0, ed=0; float emk=0.f;
  if (lt<64){ es=srcg[lt]; ed=dstg[lt]; emk=1.f; }
  const float4 brelv = *(const float4*)brel;
  const int bi4=(lt&31)<<2;
  const float4 blv0=*(const float4*)(bl       + bi4);
  const float4 blv1=*(const float4*)(bl + 128 + bi4);
  const float4 blv2=*(const float4*)(bl + 256 + bi4);
  const float4 blv3=*(const float4*)(bl + 384 + bi4);
  const float linb_s = linb[lt>>2];
  asm volatile("" ::: "memory");
  stageW(wrel,  wrelL,  512, wid, lane);
  stageW(wroot, wrootL, 512, wid, lane);
  stageW(Wl,    slotA, 16384, wid, lane);            // W1

  auto build_dense=[&](int kk, float wlane, bool with_ts){
    const float4 z4={0.f,0.f,0.f,0.f};
    *(float4*)&Adn[lt<<2]=z4;
    *(float4*)&Mdn[lt<<2]=z4;
    const bool act=(emk!=0.f);
    int mycnt=0;
    for (int v=0;v<kk;++v){
      const unsigned long long m=__ballot(act&&(ed==v));
      if (lt==v) mycnt=__popcll(m);
    }
    const float dinvl=rsqrtf(1.f+(float)mycnt);
    const float dvs=__shfl(dinvl,es,64);
    const float dvd=__shfl(dinvl,ed,64);
    if (act){
      atomicAdd(&Adn[ed*16+es], dvs*dvd*wlane);
      atomicAdd(&Mdn[ed*16+es], 1.f);
    }
    if (lt<kk){
      const float tv = with_ts ? tsA[lt] : 1.f;
      atomicAdd(&Adn[lt*17], dinvl*dinvl*tv);
    }
  };
  auto doE=[&](int n,int k,float bv,bool rebuild){
    if (lt<64){
      const float d1s=(lt<n)? d1P[lt<<2] : 0.f;
      float sc=-INFINITY;
      if (lt<n){
        float acc=d2P[lt<<2]+bv;
        for (int u=0;u<n;++u) acc += Mdn[lt*16+u]*__shfl(d1s,u,64);
        sc=acc;
      }
      int rank=0;
      for (int u=0;u<n;++u){
        const float su=__shfl(sc,u,64);
        rank += (su>sc || (su==sc && u<lt)) ? 1:0;
      }
      const int kept=(lt<n && rank<k)?1:0;
      const int pos=kept?rank:0;
      const float tval=kept?tanhf(sc):0.f;
      if (kept){ permA[rank]=lt; tsA[rank]=tval; }
      const float ts_src=__shfl(tval,es,64);
      const int ks=__shfl(kept,es,64), kd=__shfl(kept,ed,64);
      const int ps=__shfl(pos,es,64),  pd=__shfl(pos,ed,64);
      emk *= (float)(ks&kd);
      es=ps; ed=pd;
      if (rebuild) build_dense(k, ts_src, true);
    }
  };
  auto doB=[&](int n){
    if (lt<(n<<5)){
      const int v=lt>>5, j4=(lt&31)<<2;
      float4 a={0.f,0.f,0.f,0.f};
      for (int u=0;u<n;++u){
        const float w=Adn[v*16+u];
        const float4 xs=*(const float4*)&XBx[permA[u]][j4];
        a.x+=w*xs.x; a.y+=w*xs.y; a.z+=w*xs.z; a.w+=w*xs.w;
      }
      *(float4*)&ZBraw[(v<<7)+j4]=a;
    }
  };
  auto creduce2=[&](int F, int N, int L, float4 bl4){
    if (lt < (N<<5)){
      const int v=lt>>5, c4=lt&31;
      const float4* P4=(const float4*)PBf;
      float4 acc=bl4;
      for (int fp=0; fp<(F>>1); ++fp){
        const float4 p=P4[(fp*N+v)*32+c4];
        acc.x+=p.x; acc.y+=p.y; acc.z+=p.z; acc.w+=p.w;
      }
      float4 o;
      o.x=fmaxf(acc.x,0.f); o.y=fmaxf(acc.y,0.f);
      o.z=fmaxf(acc.z,0.f); o.w=fmaxf(acc.w,0.f);
      *(float4*)&XBx[v][c4<<2]=o;
      const float4 wr4=*(const float4*)&wrelL[(L<<7)+(c4<<2)];
      const float4 wo4=*(const float4*)&wrootL[(L<<7)+(c4<<2)];
      float p1=o.x*wr4.x+o.y*wr4.y+o.z*wr4.z+o.w*wr4.w;
      float p2=o.x*wo4.x+o.y*wo4.y+o.z*wo4.z+o.w*wo4.w;
      p1=hsum32(p1); p2=hsum32(p2);
      if ((lane&31)==0){ d1P[v<<2]=p1; d2P[v<<2]=p2; }
    }
  };

  // P1: stage x + layer-0 A/M
  #pragma unroll
  for (int r=0;r<4;++r){
    const int i=lt+(r<<9), v=i>>7, f=i&127;
    XBx[v][f]=xv[r];
  }
  if (lt<64) build_dense(16, 1.f, false);
  bar_lds();

  // P2: B0 — z0 = A @ x (16 x 48) stride 48
  if (lt<256){
    const int v=lt>>4, j4=(lt&15)<<2;
    if (j4<48){
      float4 a={0.f,0.f,0.f,0.f};
      for (int u=0;u<16;++u){
        const float w=Adn[v*16+u];
        const float4 xs=*(const float4*)&XBx[u][j4];
        a.x+=w*xs.x; a.y+=w*xs.y; a.z+=w*xs.z; a.w+=w*xs.w;
      }
      *(float4*)&ZBraw[v*48+j4]=a;
    }
  }
  bar_vm8();                                  // retire wrel/wroot; W1 flies

  // P3: C0 — x = relu(z0 @ W0 + b0) + score-dot epilogue (W0 global)
  {
    const int v=lt>>5, c4=lt&31, j4=c4<<2;
    const float* zrow=&ZBraw[v*48];
    float4 a={0.f,0.f,0.f,0.f};
    #pragma unroll
    for (int bb=0;bb<2;++bb){
      float4 wr[16]; float zr[16];
      #pragma unroll
      for (int t=0;t<16;++t){ wr[t]=*(const float4*)(W0+(bb*16+t)*128+j4); zr[t]=zrow[bb*16+t]; }
      #pragma unroll
      for (int t=0;t<16;++t){ a.x+=zr[t]*wr[t].x; a.y+=zr[t]*wr[t].y; a.z+=zr[t]*wr[t].z; a.w+=zr[t]*wr[t].w; }
    }
    { float4 wr[13]; float zr[13];
      #pragma unroll
      for (int t=0;t<13;++t){ wr[t]=*(const float4*)(W0+(32+t)*128+j4); zr[t]=zrow[32+t]; }
      #pragma unroll
      for (int t=0;t<13;++t){ a.x+=zr[t]*wr[t].x; a.y+=zr[t]*wr[t].y; a.z+=zr[t]*wr[t].z; a.w+=zr[t]*wr[t].w; }
    }
    float4 ox;
    ox.x=fmaxf(a.x+blv0.x,0.f); ox.y=fmaxf(a.y+blv0.y,0.f);
    ox.z=fmaxf(a.z+blv0.z,0.f); ox.w=fmaxf(a.w+blv0.w,0.f);
    *(float4*)&XBx[v][j4]=ox;
    const float4 wr4=*(const float4*)&wrelL[j4];
    const float4 wo4=*(const float4*)&wrootL[j4];
    float p1=ox.x*wr4.x+ox.y*wr4.y+ox.z*wr4.z+ox.w*wr4.w;
    float p2=ox.x*wo4.x+ox.y*wo4.y+ox.z*wo4.z+ox.w*wo4.w;
    p1=hsum32(p1); p2=hsum32(p2);
    if ((lane&31)==0){
      const int vv=(wid<<1)|(lane>>5);
      d1P[vv<<2]=p1; d2P[vv<<2]=p2;
    }
  }
  // FC0 half-weights -> VGPRs, issued BEFORE stageW(W2): in-order vmcnt
  // retirement then never makes a counted barrier wait on W2. (R12 bug fix.)
  float4 wfc[16];
  #pragma unroll
  for (int t=0;t<16;++t)
    wfc[t]=*(const float4*)(fcW + ((br<<7)+f0fc+t)*256 + (qfc<<2));
  asm volatile("" ::: "memory");               // pin issue order vs DMA below
  stageW(Wl+16384, slotB, 16384, wid, lane);   // W2
  bar_lds();

  doE(16, 8, brelv.x, true);    bar_lds();     // E0
  doB(8);                       bar_vm8();     // B1 (retire W1+wfc; W2 flies)
  cmain2<4,2,8>(lt, slotA, ZBraw, PBf);  bar_lds();   // C1m
  creduce2(4, 8, 1, blv1);      bar_lds();     // C1r
  stageW(Wl+32768, slotA, 16384, wid, lane);   // W3
  doE(8, 4, brelv.y, true);     bar_lds();     // E1
  doB(4);                       bar_vm8();     // B2 (retire W2; W3 flies)
  cmain2<8,2,4>(lt, slotB, ZBraw, PBf); bar_lds();    // C2m
  creduce2(8, 4, 2, blv2);      bar_lds();     // C2r
  stageW(linWg, slotB, 16384, wid, lane);      // linW
  doE(4, 2, brelv.z, true);     bar_lds();     // E2
  doB(2);                       bar_vm8();     // B3 (retire W3; linW flies)
  cmain2<8,1,2>(lt, slotA, ZBraw, PBf); bar_lds();    // C3m
  creduce2(8, 2, 3, blv3);      bar_vm0();     // C3r; drain linW

  // readout with inline E3 (every thread computes the 2-node top-1 locally)
  {
    const float bv=brelv.w;
    const float s0v = d2P[0]+bv + Mdn[0] *d1P[0] + Mdn[1] *d1P[4];
    const float s1v = d2P[4]+bv + Mdn[16]*d1P[0] + Mdn[17]*d1P[4];
    const int   prow = (s1v>s0v) ? 1 : 0;      // stable argmax (tie -> node 0)
    const float tsf  = tanhf(prow ? s1v : s0v);
    const int oj=lt>>2, fh=lt&3;
    float p=0.f;
    #pragma unroll
    for (int i=0;i<32;++i){
      const int f=(fh<<5)+i;
      p += XBx[prow][f]*slotB[f*128+oj];
    }
    p+=__shfl_xor(p,1,64); p+=__shfl_xor(p,2,64);
    if (fh==0) yA[oj]=p*tsf+linb_s;
  }
  bar_lds();
  // log-softmax -> fcin
  if (lt<128){
    const int ln=lt&63;
    const float a0=yA[ln], b0=yA[64+ln];
    const float m=wmax(fmaxf(a0,b0));
    const float sum=wsum(expf(a0-m)+expf(b0-m));
    const float lse=m+logf(sum);
    fcin[lt]=yA[lt]-lse;
  }
  bar_lds();
  // FC0 half-GEMV: partial = logprobs_half @ fcW0[br*128.., :]
  {
    float4 a={0.f,0.f,0.f,0.f};
    #pragma unroll
    for (int t=0;t<16;++t){
      const float zv=fcin[f0fc+t];
      a.x+=zv*wfc[t].x; a.y+=zv*wfc[t].y; a.z+=zv*wfc[t].z; a.w+=zv*wfc[t].w;
    }
    #pragma unroll
    for (int m=8;m<64;m<<=1){
      a.x+=__shfl_xor(a.x,m,64); a.y+=__shfl_xor(a.y,m,64);
      a.z+=__shfl_xor(a.z,m,64); a.w+=__shfl_xor(a.w,m,64);
    }
    if (lane<8){
      float* dst=wsOut+(qfc<<2);
      astore(dst+0,a.x); astore(dst+1,a.y); astore(dst+2,a.z); astore(dst+3,a.w);
    }
  }
  bar_vm0();
  if (lt==0) __hip_atomic_store(wsFlag, MAGIC, __ATOMIC_RELEASE, __HIP_MEMORY_SCOPE_AGENT);
}

extern "C" void kernel_launch(void* const* d_in, const int* in_sizes, int n_in,
                              void* d_out, int out_size, void* d_ws, size_t ws_size,
                              hipStream_t stream){
  // setup_inputs() DICT order (fc/ln block precedes gnn params):
  //  0 gp_x  1 sp_x  2 gp_src  3 gp_dst  4 sp_src  5 sp_dst
  //  6 fcW   7 fcb   8 lnw     9 lnb
  // 10 g_W0 11 g_W  12 g_b   13 g_pWrel 14 g_pbrel 15 g_pWroot 16 g_linW 17 g_linb
  // 18 s_W0 19 s_W  20 s_b   21 s_pWrel 22 s_pbrel 23 s_pWroot 24 s_linW 25 s_linb
  net_kernel<<<19,512,0,stream>>>(
    (const float*)d_in[0],(const float*)d_in[1],
    (const int*)d_in[2],(const int*)d_in[3],(const int*)d_in[4],(const int*)d_in[5],
    (const float*)d_in[10],(const float*)d_in[11],(const float*)d_in[12],(const float*)d_in[13],
    (const float*)d_in[14],(const float*)d_in[15],(const float*)d_in[16],(const float*)d_in[17],
    (const float*)d_in[18],(const float*)d_in[19],(const float*)d_in[20],(const float*)d_in[21],
    (const float*)d_in[22],(const float*)d_in[23],(const float*)d_in[24],(const float*)d_in[25],
    (const float*)d_in[6],(const float*)d_in[7],(const float*)d_in[8],(const float*)d_in[9],
    (float*)d_ws,(float*)d_out);
}

// Round 16
// 23.718 us; speedup vs baseline: 1.0193x; 1.0193x over previous
//
#include <hip/hip_runtime.h>
#include <math.h>

#define MAGIC 0x5F3759DFu
typedef unsigned int u32;

__device__ __forceinline__ void bar_lds(){
  asm volatile("s_waitcnt lgkmcnt(0)\n\ts_barrier" ::: "memory");
}
__device__ __forceinline__ void bar_vm0(){
  asm volatile("s_waitcnt vmcnt(0) lgkmcnt(0)\n\ts_barrier" ::: "memory");
}
__device__ __forceinline__ void bar_vm8(){
  asm volatile("s_waitcnt vmcnt(8) lgkmcnt(0)\n\ts_barrier" ::: "memory");
}

__device__ inline float wsum(float v){
  #pragma unroll
  for (int o=32;o;o>>=1) v += __shfl_xor(v,o,64);
  return v;
}
__device__ inline float wmax(float v){
  #pragma unroll
  for (int o=32;o;o>>=1) v = fmaxf(v,__shfl_xor(v,o,64));
  return v;
}
__device__ inline float hsum32(float v){
  #pragma unroll
  for (int o=16;o;o>>=1) v += __shfl_xor(v,o,64);
  return v;
}
__device__ __forceinline__ void stageW(const float* g, float* l, int nfloats,
                                       int wid, int lane){
  const int nch = nfloats>>8;
  for (int c=wid; c<nch; c+=8)
    __builtin_amdgcn_global_load_lds(
      (__attribute__((address_space(1))) u32*)(void*)(g+(c<<8)+(lane<<2)),
      (__attribute__((address_space(3))) u32*)(void*)(l+(c<<8)), 16, 0, 0);
}
__device__ __forceinline__ void pf(const float* p, int nfloats, int tid){
  float4 acc={0.f,0.f,0.f,0.f};
  const int nq=nfloats>>2;
  for (int i=tid;i<nq;i+=512){
    const float4 v=((const float4*)p)[i];
    acc.x+=v.x; acc.y+=v.y; acc.z+=v.z; acc.w+=v.w;
  }
  asm volatile("" :: "v"(acc.x),"v"(acc.y),"v"(acc.z),"v"(acc.w));
}
__device__ __forceinline__ void poll1(const u32* f, int lane){
  u32 v=0;
  do {
    if (lane==0) v=__hip_atomic_load(f,__ATOMIC_ACQUIRE,__HIP_MEMORY_SCOPE_AGENT);
    v=(u32)__shfl((int)v,0,64);
    if (v!=MAGIC) __builtin_amdgcn_s_sleep(1);
  } while (v!=MAGIC);
}
__device__ __forceinline__ float aload(const float* p){
  return __hip_atomic_load(p,__ATOMIC_RELAXED,__HIP_MEMORY_SCOPE_AGENT);
}
__device__ __forceinline__ void astore(float* p, float v){
  __hip_atomic_store(p,v,__ATOMIC_RELAXED,__HIP_MEMORY_SCOPE_AGENT);
}

// amp-reduced C-main (proven R14)
template<int F,int VH,int N>
__device__ __forceinline__ void cmain2(int lt, const float* slot,
                                       const float* ZBp, float* PBp){
  constexpr int CH = 128/F;
  const int c4 = lt&31, r = lt>>5;
  const int fh = r & (F-1), vh = r / F;
  const int f0 = fh*CH;
  const float4* slot4 = (const float4*)slot;
  float4 acc[VH];
  #pragma unroll
  for (int i=0;i<VH;++i) acc[i]=make_float4(0.f,0.f,0.f,0.f);
  #pragma unroll
  for (int f=0; f<CH; ++f){
    const float4 w4 = slot4[(f0+f)*32 + c4];
    #pragma unroll
    for (int i=0;i<VH;++i){
      const float zv = ZBp[((vh*VH+i)<<7) + f0 + f];
      acc[i].x+=zv*w4.x; acc[i].y+=zv*w4.y; acc[i].z+=zv*w4.z; acc[i].w+=zv*w4.w;
    }
  }
  #pragma unroll
  for (int i=0;i<VH;++i){
    acc[i].x+=__shfl_xor(acc[i].x,32,64);
    acc[i].y+=__shfl_xor(acc[i].y,32,64);
    acc[i].z+=__shfl_xor(acc[i].z,32,64);
    acc[i].w+=__shfl_xor(acc[i].w,32,64);
  }
  if (!(r&1)){
    const int fp = fh>>1;
    float4* P4=(float4*)PBp;
    #pragma unroll
    for (int i=0;i<VH;++i)
      P4[(fp*N + vh*VH + i)*32 + c4] = acc[i];
  }
}

// ws float layout: pg[0..255] flagG@256 | ps[320..575] flagS@576
//                  h1[640..895] flag@896 | h2[960..1215] flag@1216
__global__ __launch_bounds__(512,1) void net_kernel(
    const float* __restrict__ gp_x, const float* __restrict__ sp_x,
    const int* __restrict__ gp_src, const int* __restrict__ gp_dst,
    const int* __restrict__ sp_src, const int* __restrict__ sp_dst,
    const float* __restrict__ g_W0, const float* __restrict__ g_W,
    const float* __restrict__ g_b,  const float* __restrict__ g_pWrel,
    const float* __restrict__ g_pbrel, const float* __restrict__ g_pWroot,
    const float* __restrict__ g_linW, const float* __restrict__ g_linb,
    const float* __restrict__ s_W0, const float* __restrict__ s_W,
    const float* __restrict__ s_b,  const float* __restrict__ s_pWrel,
    const float* __restrict__ s_pbrel, const float* __restrict__ s_pWroot,
    const float* __restrict__ s_linW, const float* __restrict__ s_linb,
    const float* __restrict__ fcW, const float* __restrict__ fcb,
    const float* __restrict__ lnw, const float* __restrict__ lnb,
    float* __restrict__ wsbuf, float* __restrict__ out)
{
  __shared__ __align__(16) float slotA[16384];   // W1 -> W3 (DMA)
  __shared__ __align__(16) float slotB[16384];   // W2 -> linW (DMA)
  __shared__ __align__(16) float XBx[16][128];
  __shared__ __align__(16) float ZBraw[1024];
  __shared__ __align__(16) float PBf[2048];      // C-phase partials (8KB)
  __shared__ __align__(16) float wrelL[512], wrootL[512];
  __shared__ __align__(16) float Adn[256], Mdn[256];
  __shared__ float d1P[64], d2P[64];
  __shared__ float yA[128];
  __shared__ float tsA[8]; __shared__ int permA[8];
  __shared__ float fcin[256]; __shared__ float wpart[16];
  __shared__ int   cntL[16];

  const int lt  = threadIdx.x;
  const int bid = blockIdx.x;
  const int wid = lt>>6, lane = lt&63;
  const int qfc = (wid<<3)+(lane&7);             // output quad 0..63

  // ============ prefetch army (bids 5..18): fine slices ============
  if (bid >= 5){
    if (bid==5){ pf(g_W0,5760,lt); pf(g_pWrel,512,lt); pf(g_pWroot,512,lt);
                 pf(g_b,512,lt);   pf(g_linb,128,lt); }
    else if (bid==6){ pf(s_W0,5760,lt); pf(s_pWrel,512,lt); pf(s_pWroot,512,lt);
                 pf(s_b,512,lt);   pf(s_linb,128,lt); }
    else if (bid<=10) pf(g_W + (bid-7)*12288, 12288, lt);
    else if (bid<=14) pf(s_W + (bid-11)*12288, 12288, lt);
    else if (bid<=16) pf(g_linW + (bid-15)*8192, 8192, lt);
    else              pf(s_linW + (bid-17)*8192, 8192, lt);
    return;
  }

  // ============ FC pipeline blocks (bids 2,3,4 -> layers 1,2,3) ============
  if (bid >= 2){
    const int L = bid-1;                         // 1,2,3
    const int f0fc=(lane>>3)<<5;                 // 32-input chunk
    float4 wr[32];
    #pragma unroll
    for (int t=0;t<32;++t) wr[t]=*(const float4*)(fcW+(L<<16)+(f0fc+t)*256+(qfc<<2));
    const float4 bb=*(const float4*)(fcb+(L<<8)+(qfc<<2));
    float4 lw={0,0,0,0}, lb2={0,0,0,0};
    if (L<3){ lw=*(const float4*)(lnw+(L<<8)+(qfc<<2)); lb2=*(const float4*)(lnb+(L<<8)+(qfc<<2)); }

    float zr[32];
    if (bid==2){
      // FC1: sum worker FC0-partials + fcb0, LN0, relu -> fcin
      float b0=0.f,w0=0.f,l0=0.f;
      if (lt<256){ b0=fcb[lt]; w0=lnw[lt]; l0=lnb[lt]; }
      poll1((const u32*)(wsbuf+256), lane);
      poll1((const u32*)(wsbuf+576), lane);
      float h=0.f;
      if (lt<256){
        h = aload(wsbuf+lt) + aload(wsbuf+320+lt) + b0;
        float s=wsum(h), s2=wsum(h*h);
        if (lane==0){ wpart[wid]=s; wpart[8+wid]=s2; }
      }
      bar_lds();
      if (lt<256){
        const float S =wpart[0]+wpart[1]+wpart[2]+wpart[3];
        const float S2=wpart[8]+wpart[9]+wpart[10]+wpart[11];
        const float mu=S*(1.f/256.f);
        const float ri=rsqrtf(S2*(1.f/256.f)-mu*mu+1e-5f);
        fcin[lt]=fmaxf((h-mu)*ri*w0+l0,0.f);
      }
      bar_lds();
      #pragma unroll
      for (int t=0;t<32;++t) zr[t]=fcin[f0fc+t];
    } else {
      const int floff = (bid==3)?896:1216;
      const int srcoff= (bid==3)?640:960;
      poll1((const u32*)(wsbuf+floff), lane);
      #pragma unroll
      for (int t=0;t<32;++t) zr[t]=aload(wsbuf+srcoff+f0fc+t);
    }
    float4 a={0.f,0.f,0.f,0.f};
    #pragma unroll
    for (int t=0;t<32;++t){
      a.x+=zr[t]*wr[t].x; a.y+=zr[t]*wr[t].y; a.z+=zr[t]*wr[t].z; a.w+=zr[t]*wr[t].w;
    }
    #pragma unroll
    for (int m=8;m<64;m<<=1){
      a.x+=__shfl_xor(a.x,m,64); a.y+=__shfl_xor(a.y,m,64);
      a.z+=__shfl_xor(a.z,m,64); a.w+=__shfl_xor(a.w,m,64);
    }
    if (bid==4){
      if (lane<8){
        float4 r; r.x=a.x+bb.x; r.y=a.y+bb.y; r.z=a.z+bb.z; r.w=a.w+bb.w;
        *(float4*)(out+(qfc<<2))=r;
      }
      return;
    }
    const bool act=(lane<8);
    float4 hv={0.f,0.f,0.f,0.f};
    if (act){
      hv.x=a.x+bb.x; hv.y=a.y+bb.y; hv.z=a.z+bb.z; hv.w=a.w+bb.w;
      float s=hv.x+hv.y+hv.z+hv.w;
      float s2=hv.x*hv.x+hv.y*hv.y+hv.z*hv.z+hv.w*hv.w;
      #pragma unroll
      for (int m=1;m<8;m<<=1){ s+=__shfl_xor(s,m,64); s2+=__shfl_xor(s2,m,64); }
      if (lane==0){ wpart[wid]=s; wpart[8+wid]=s2; }
    }
    bar_lds();
    if (act){
      float S=0.f,S2=0.f;
      #pragma unroll
      for (int w2=0;w2<8;++w2){ S+=wpart[w2]; S2+=wpart[8+w2]; }
      const float mu=S*(1.f/256.f);
      const float ri=rsqrtf(S2*(1.f/256.f)-mu*mu+1e-5f);
      float* dst=wsbuf + ((bid==2)?640:960) + (qfc<<2);
      astore(dst+0,fmaxf((hv.x-mu)*ri*lw.x+lb2.x,0.f));
      astore(dst+1,fmaxf((hv.y-mu)*ri*lw.y+lb2.y,0.f));
      astore(dst+2,fmaxf((hv.z-mu)*ri*lw.z+lb2.z,0.f));
      astore(dst+3,fmaxf((hv.w-mu)*ri*lw.w+lb2.w,0.f));
    }
    bar_vm0();
    if (lt==0) __hip_atomic_store((u32*)(wsbuf+((bid==2)?896:1216)),MAGIC,__ATOMIC_RELEASE,__HIP_MEMORY_SCOPE_AGENT);
    return;
  }

  // ============ GNN worker blocks (bids 0,1) ============
  const int br = bid;
  const float* x0    = br ? sp_x    : gp_x;
  const int*   srcg  = br ? sp_src  : gp_src;
  const int*   dstg  = br ? sp_dst  : gp_dst;
  const float* W0    = br ? s_W0    : g_W0;
  const float* Wl    = br ? s_W     : g_W;
  const float* bl    = br ? s_b     : g_b;
  const float* wrel  = br ? s_pWrel : g_pWrel;
  const float* brel  = br ? s_pbrel : g_pbrel;
  const float* wroot = br ? s_pWroot: g_pWroot;
  const float* linWg = br ? s_linW  : g_linW;
  const float* linb  = br ? s_linb  : g_linb;
  float* wsOut = wsbuf + br*320;
  u32*   wsFlag = (u32*)(wsbuf + 256 + br*320);
  const int f0fc=(lane>>3)<<4;                   // 16-input chunk (FC0 half)

  float xv[4];
  #pragma unroll
  for (int r=0;r<4;++r){
    const int i=lt+(r<<9), v=i>>7, f=i&127;
    xv[r] = (f<45)? x0[v*45+f] : 0.f;
  }
  int es=0, ed=0; float emk=0.f;
  if (lt<64){ es=srcg[lt]; ed=dstg[lt]; emk=1.f; }
  const float4 brelv = *(const float4*)brel;
  const int bi4=(lt&31)<<2;
  const float4 blv0=*(const float4*)(bl       + bi4);
  const float4 blv1=*(const float4*)(bl + 128 + bi4);
  const float4 blv2=*(const float4*)(bl + 256 + bi4);
  const float4 blv3=*(const float4*)(bl + 384 + bi4);
  const float linb_s = linb[lt>>2];
  asm volatile("" ::: "memory");
  stageW(wrel,  wrelL,  512, wid, lane);
  stageW(wroot, wrootL, 512, wid, lane);
  stageW(Wl,    slotA, 16384, wid, lane);            // W1

  // wave0 dense A/M builder: LDS-atomic degree histogram (deterministic:
  // integer counts; per-cell float summands identical values)
  auto build_dense=[&](int kk, float wlane, bool with_ts){
    const float4 z4={0.f,0.f,0.f,0.f};
    *(float4*)&Adn[lt<<2]=z4;
    *(float4*)&Mdn[lt<<2]=z4;
    if (lt<16) cntL[lt]=0;
    const bool act=(emk!=0.f);
    if (act) atomicAdd(&cntL[ed],1);
    const float dinvl = (lt<16)? rsqrtf(1.f+(float)cntL[lt]) : 0.f;
    const float dvs=__shfl(dinvl,es,64);
    const float dvd=__shfl(dinvl,ed,64);
    if (act){
      atomicAdd(&Adn[ed*16+es], dvs*dvd*wlane);
      atomicAdd(&Mdn[ed*16+es], 1.f);
    }
    if (lt<kk){
      const float tv = with_ts ? tsA[lt] : 1.f;
      atomicAdd(&Adn[lt*17], dinvl*dinvl*tv);
    }
  };
  auto doE=[&](int n,int k,float bv,bool rebuild){
    if (lt<64){
      float sc=-INFINITY;
      if (lt<n){
        float acc=d2P[lt<<2]+bv;
        for (int u=0;u<n;++u) acc += Mdn[lt*16+u]*d1P[u<<2];
        sc=acc;
      }
      int rank=0;
      for (int u=0;u<n;++u){
        const float su=__shfl(sc,u,64);
        rank += (su>sc || (su==sc && u<lt)) ? 1:0;
      }
      const int kept=(lt<n && rank<k)?1:0;
      const int pos=kept?rank:0;
      const float tval=kept?tanhf(sc):0.f;
      if (kept){ permA[rank]=lt; tsA[rank]=tval; }
      const float ts_src=__shfl(tval,es,64);
      const int ks=__shfl(kept,es,64), kd=__shfl(kept,ed,64);
      const int ps=__shfl(pos,es,64),  pd=__shfl(pos,ed,64);
      emk *= (float)(ks&kd);
      es=ps; ed=pd;
      if (rebuild) build_dense(k, ts_src, true);
    }
  };
  auto doB=[&](int n){
    if (lt<(n<<5)){
      const int v=lt>>5, j4=(lt&31)<<2;
      float4 a={0.f,0.f,0.f,0.f};
      for (int u=0;u<n;++u){
        const float w=Adn[v*16+u];
        const float4 xs=*(const float4*)&XBx[permA[u]][j4];
        a.x+=w*xs.x; a.y+=w*xs.y; a.z+=w*xs.z; a.w+=w*xs.w;
      }
      *(float4*)&ZBraw[(v<<7)+j4]=a;
    }
  };
  auto creduce2=[&](int F, int N, int L, float4 bl4){
    if (lt < (N<<5)){
      const int v=lt>>5, c4=lt&31;
      const float4* P4=(const float4*)PBf;
      float4 acc=bl4;
      for (int fp=0; fp<(F>>1); ++fp){
        const float4 p=P4[(fp*N+v)*32+c4];
        acc.x+=p.x; acc.y+=p.y; acc.z+=p.z; acc.w+=p.w;
      }
      float4 o;
      o.x=fmaxf(acc.x,0.f); o.y=fmaxf(acc.y,0.f);
      o.z=fmaxf(acc.z,0.f); o.w=fmaxf(acc.w,0.f);
      *(float4*)&XBx[v][c4<<2]=o;
      const float4 wr4=*(const float4*)&wrelL[(L<<7)+(c4<<2)];
      const float4 wo4=*(const float4*)&wrootL[(L<<7)+(c4<<2)];
      float p1=o.x*wr4.x+o.y*wr4.y+o.z*wr4.z+o.w*wr4.w;
      float p2=o.x*wo4.x+o.y*wo4.y+o.z*wo4.z+o.w*wo4.w;
      p1=hsum32(p1); p2=hsum32(p2);
      if ((lane&31)==0){ d1P[v<<2]=p1; d2P[v<<2]=p2; }
    }
  };

  // P1: stage x + layer-0 A/M
  #pragma unroll
  for (int r=0;r<4;++r){
    const int i=lt+(r<<9), v=i>>7, f=i&127;
    XBx[v][f]=xv[r];
  }
  if (lt<64) build_dense(16, 1.f, false);
  bar_lds();

  // P2: B0 — z0 = A @ x (16 x 48) stride 48
  if (lt<256){
    const int v=lt>>4, j4=(lt&15)<<2;
    if (j4<48){
      float4 a={0.f,0.f,0.f,0.f};
      for (int u=0;u<16;++u){
        const float w=Adn[v*16+u];
        const float4 xs=*(const float4*)&XBx[u][j4];
        a.x+=w*xs.x; a.y+=w*xs.y; a.z+=w*xs.z; a.w+=w*xs.w;
      }
      *(float4*)&ZBraw[v*48+j4]=a;
    }
  }
  bar_vm8();                                  // retire wrel/wroot; W1 flies

  // P3: C0 — x = relu(z0 @ W0 + b0) + score-dot epilogue (W0 global)
  {
    const int v=lt>>5, c4=lt&31, j4=c4<<2;
    const float* zrow=&ZBraw[v*48];
    float4 a={0.f,0.f,0.f,0.f};
    #pragma unroll
    for (int bb=0;bb<2;++bb){
      float4 wr[16]; float zr[16];
      #pragma unroll
      for (int t=0;t<16;++t){ wr[t]=*(const float4*)(W0+(bb*16+t)*128+j4); zr[t]=zrow[bb*16+t]; }
      #pragma unroll
      for (int t=0;t<16;++t){ a.x+=zr[t]*wr[t].x; a.y+=zr[t]*wr[t].y; a.z+=zr[t]*wr[t].z; a.w+=zr[t]*wr[t].w; }
    }
    { float4 wr[13]; float zr[13];
      #pragma unroll
      for (int t=0;t<13;++t){ wr[t]=*(const float4*)(W0+(32+t)*128+j4); zr[t]=zrow[32+t]; }
      #pragma unroll
      for (int t=0;t<13;++t){ a.x+=zr[t]*wr[t].x; a.y+=zr[t]*wr[t].y; a.z+=zr[t]*wr[t].z; a.w+=zr[t]*wr[t].w; }
    }
    float4 ox;
    ox.x=fmaxf(a.x+blv0.x,0.f); ox.y=fmaxf(a.y+blv0.y,0.f);
    ox.z=fmaxf(a.z+blv0.z,0.f); ox.w=fmaxf(a.w+blv0.w,0.f);
    *(float4*)&XBx[v][j4]=ox;
    const float4 wr4=*(const float4*)&wrelL[j4];
    const float4 wo4=*(const float4*)&wrootL[j4];
    float p1=ox.x*wr4.x+ox.y*wr4.y+ox.z*wr4.z+ox.w*wr4.w;
    float p2=ox.x*wo4.x+ox.y*wo4.y+ox.z*wo4.z+ox.w*wo4.w;
    p1=hsum32(p1); p2=hsum32(p2);
    if ((lane&31)==0){
      const int vv=(wid<<1)|(lane>>5);
      d1P[vv<<2]=p1; d2P[vv<<2]=p2;
    }
  }
  // FC0 half-weights -> VGPRs BEFORE stageW(W2) (R12 lesson); colsum in regs
  float4 wfc[16];
  #pragma unroll
  for (int t=0;t<16;++t)
    wfc[t]=*(const float4*)(fcW + ((br<<7)+f0fc+t)*256 + (qfc<<2));
  asm volatile("" ::: "memory");               // pin issue order vs DMA below
  stageW(Wl+16384, slotB, 16384, wid, lane);   // W2
  float4 csum={0.f,0.f,0.f,0.f};
  #pragma unroll
  for (int t=0;t<16;++t){ csum.x+=wfc[t].x; csum.y+=wfc[t].y; csum.z+=wfc[t].z; csum.w+=wfc[t].w; }
  bar_lds();

  doE(16, 8, brelv.x, true);    bar_lds();     // E0
  doB(8);                       bar_vm8();     // B1 (retire W1+wfc; W2 flies)
  cmain2<4,2,8>(lt, slotA, ZBraw, PBf);  bar_lds();   // C1m
  creduce2(4, 8, 1, blv1);      bar_lds();     // C1r
  stageW(Wl+32768, slotA, 16384, wid, lane);   // W3
  doE(8, 4, brelv.y, true);     bar_lds();     // E1
  doB(4);                       bar_vm8();     // B2 (retire W2; W3 flies)
  cmain2<8,2,4>(lt, slotB, ZBraw, PBf); bar_lds();    // C2m
  creduce2(8, 4, 2, blv2);      bar_lds();     // C2r
  stageW(linWg, slotB, 16384, wid, lane);      // linW
  doE(4, 2, brelv.z, true);     bar_lds();     // E2
  doB(2);                       bar_vm8();     // B3 (retire W3; linW flies)
  cmain2<8,1,2>(lt, slotA, ZBraw, PBf); bar_lds();    // C3m
  creduce2(8, 2, 3, blv3);      bar_vm0();     // C3r; drain linW

  // RO with inline E3 (every thread computes the 2-node top-1 locally)
  {
    const float bv=brelv.w;
    const float s0v = d2P[0]+bv + Mdn[0] *d1P[0] + Mdn[1] *d1P[4];
    const float s1v = d2P[4]+bv + Mdn[16]*d1P[0] + Mdn[17]*d1P[4];
    const int   prow = (s1v>s0v) ? 1 : 0;      // stable argmax (tie -> node 0)
    const float tsf  = tanhf(prow ? s1v : s0v);
    const int oj=lt>>2, fh=lt&3;
    float p=0.f;
    #pragma unroll
    for (int i=0;i<32;++i){
      const int f=(fh<<5)+i;
      p += XBx[prow][f]*slotB[f*128+oj];
    }
    p+=__shfl_xor(p,1,64); p+=__shfl_xor(p,2,64);
    if (fh==0) yA[oj]=p*tsf+linb_s;
  }
  bar_lds();
  // TAIL (merged): lse (per-wave redundant) + FC0 half-GEMV with colsum fold
  //   sum_i (y_i - lse) W_ij = sum_i y_i W_ij - lse * colsum_j
  {
    const float a0=yA[lane], b0=yA[64+lane];
    const float m=wmax(fmaxf(a0,b0));
    const float sum=wsum(expf(a0-m)+expf(b0-m));
    const float lse=m+logf(sum);
    float4 a={0.f,0.f,0.f,0.f};
    #pragma unroll
    for (int t=0;t<16;++t){
      const float zv=yA[f0fc+t];
      a.x+=zv*wfc[t].x; a.y+=zv*wfc[t].y; a.z+=zv*wfc[t].z; a.w+=zv*wfc[t].w;
    }
    float4 cs=csum;
    #pragma unroll
    for (int m2=8;m2<64;m2<<=1){
      a.x+=__shfl_xor(a.x,m2,64); a.y+=__shfl_xor(a.y,m2,64);
      a.z+=__shfl_xor(a.z,m2,64); a.w+=__shfl_xor(a.w,m2,64);
      cs.x+=__shfl_xor(cs.x,m2,64); cs.y+=__shfl_xor(cs.y,m2,64);
      cs.z+=__shfl_xor(cs.z,m2,64); cs.w+=__shfl_xor(cs.w,m2,64);
    }
    if (lane<8){
      float* dst=wsOut+(qfc<<2);
      astore(dst+0, a.x - lse*cs.x);
      astore(dst+1, a.y - lse*cs.y);
      astore(dst+2, a.z - lse*cs.z);
      astore(dst+3, a.w - lse*cs.w);
    }
  }
  bar_vm0();
  if (lt==0) __hip_atomic_store(wsFlag, MAGIC, __ATOMIC_RELEASE, __HIP_MEMORY_SCOPE_AGENT);
}

extern "C" void kernel_launch(void* const* d_in, const int* in_sizes, int n_in,
                              void* d_out, int out_size, void* d_ws, size_t ws_size,
                              hipStream_t stream){
  // setup_inputs() DICT order (fc/ln block precedes gnn params):
  //  0 gp_x  1 sp_x  2 gp_src  3 gp_dst  4 sp_src  5 sp_dst
  //  6 fcW   7 fcb   8 lnw     9 lnb
  // 10 g_W0 11 g_W  12 g_b   13 g_pWrel 14 g_pbrel 15 g_pWroot 16 g_linW 17 g_linb
  // 18 s_W0 19 s_W  20 s_b   21 s_pWrel 22 s_pbrel 23 s_pWroot 24 s_linW 25 s_linb
  net_kernel<<<19,512,0,stream>>>(
    (const float*)d_in[0],(const float*)d_in[1],
    (const int*)d_in[2],(const int*)d_in[3],(const int*)d_in[4],(const int*)d_in[5],
    (const float*)d_in[10],(const float*)d_in[11],(const float*)d_in[12],(const float*)d_in[13],
    (const float*)d_in[14],(const float*)d_in[15],(const float*)d_in[16],(const float*)d_in[17],
    (const float*)d_in[18],(const float*)d_in[19],(const float*)d_in[20],(const float*)d_in[21],
    (const float*)d_in[22],(const float*)d_in[23],(const float*)d_in[24],(const float*)d_in[25],
    (const float*)d_in[6],(const float*)d_in[7],(const float*)d_in[8],(const float*)d_in[9],
    (float*)d_ws,(float*)d_out);
}